// Round 8
// baseline (397.388 us; speedup 1.0000x reference)
//
#include <hip/hip_runtime.h>
#include <hip/hip_bf16.h>
#include <hip/hip_fp16.h>
#include <math.h>

// ---------------------------------------------------------------------------
// DynamicGCN: 3x (GCNConv -> ReLU -> *gate)
// R1: multi-block scan, hist fused into convert, dinv folded into scan C.
// R2: split-bf16 MFMA GEMM, W pre-swizzled into B-fragment order.
// R3: agg 2 nodes/wave (half-wave x float4).
// R4: self-loop folded into CSR (norm = dinv^2 exactly).
// R7: H intermediate fp16 (halved gather traffic); gemm per-wave
//     global_load_lds barrier-free pipeline (wave-private bufs + vmcnt(4)).
// R8: agg 8-deep PREDICATED edge chunks (kills the serial tail loop - avg
//     deg ~7 means the old 4-deep+tail serialized ~half the edges);
//     gate fused into wswizzle grid.
// ---------------------------------------------------------------------------

#define D 128   // feature dim (D_IN == HID == 128)

typedef __attribute__((ext_vector_type(8))) short short8;
typedef __attribute__((ext_vector_type(4))) float floatx4;

__device__ __forceinline__ unsigned bf16_rne(float x) {
    unsigned u = __float_as_uint(x);
    return (u + 0x7FFFu + ((u >> 16) & 1u)) >> 16;
}

__device__ __forceinline__ void gload_lds16(const float* g, float* l) {
    __builtin_amdgcn_global_load_lds(
        (const __attribute__((address_space(1))) unsigned int*)g,
        (__attribute__((address_space(3))) unsigned int*)l, 16, 0, 0);
}

__device__ __forceinline__ float h2f(unsigned short u) {
    return __half2float(__ushort_as_half(u));
}

// ---- edge_index convert (int64 auto-detect) + fused degree histogram ------
__global__ __launch_bounds__(256) void convert_hist_kernel(
    const int* __restrict__ w, int* __restrict__ src32,
    int* __restrict__ dst32, int* __restrict__ counts, int E)
{
    __shared__ int flag;
    if (threadIdx.x == 0) {
        int z = 0;
        for (int k = 0; k < 64; k++) z |= w[2 * k + 1];
        flag = (z == 0) ? 1 : 0;   // all odd words zero => int64 layout
    }
    __syncthreads();
    int i64 = flag;
    int total = 2 * E;
    int stride = gridDim.x * blockDim.x;
    for (int i = blockIdx.x * blockDim.x + threadIdx.x; i < total; i += stride) {
        int v = i64 ? w[2 * i] : w[i];   // little-endian low word
        if (i < E) {
            src32[i] = v;
        } else {
            dst32[i - E] = v;
            atomicAdd(&counts[v], 1);
        }
    }
}

// ------------------- multi-block exclusive scan ----------------------------
// Scans (counts[i] + 1): CSR capacity includes one self-edge per node.
#define SCHUNK 1024
__global__ __launch_bounds__(256) void scan_partial_kernel(
    const int* __restrict__ counts, int* __restrict__ bsums, int N)
{
    int base = blockIdx.x * SCHUNK + threadIdx.x * 4;
    int s = 0;
    if (base + 3 < N) {
        int4 v = *(const int4*)(counts + base);
        s = v.x + v.y + v.z + v.w + 4;
    } else {
        for (int k = 0; k < 4; k++) if (base + k < N) s += counts[base + k] + 1;
    }
    #pragma unroll
    for (int off = 1; off < 64; off <<= 1) s += __shfl_xor(s, off);
    __shared__ int wsum[4];
    int lane = threadIdx.x & 63, wid = threadIdx.x >> 6;
    if (lane == 0) wsum[wid] = s;
    __syncthreads();
    if (threadIdx.x == 0)
        bsums[blockIdx.x] = wsum[0] + wsum[1] + wsum[2] + wsum[3];
}

__global__ __launch_bounds__(1024) void scan_bsums_kernel(
    int* __restrict__ bsums, int* __restrict__ total_out, int B)
{
    int t = threadIdx.x;
    int v = (t < B) ? bsums[t] : 0;
    int lane = t & 63, wid = t >> 6;
    int s = v;
    #pragma unroll
    for (int off = 1; off < 64; off <<= 1) {
        int n = __shfl_up(s, off);
        if (lane >= off) s += n;
    }
    __shared__ int wsum[16], wpre[16];
    if (lane == 63) wsum[wid] = s;
    __syncthreads();
    if (t < 16) {
        int ws = wsum[t];
        #pragma unroll
        for (int off = 1; off < 16; off <<= 1) {
            int n = __shfl_up(ws, off);
            if (t >= off) ws += n;
        }
        wpre[t] = ws;
    }
    __syncthreads();
    int wex = wid ? wpre[wid - 1] : 0;
    if (t < B) bsums[t] = wex + (s - v);      // exclusive
    if (t == 0) *total_out = wpre[15];        // grand total -> offsets[N]
}

__global__ __launch_bounds__(256) void scan_final_kernel(
    const int* __restrict__ counts, const int* __restrict__ bsums,
    int* __restrict__ offsets, int* __restrict__ cursor,
    float* __restrict__ dinv, int N)
{
    int base = blockIdx.x * SCHUNK + threadIdx.x * 4;
    int c[4];
    bool full = (base + 3 < N);
    if (full) {
        int4 v = *(const int4*)(counts + base);
        c[0] = v.x + 1; c[1] = v.y + 1; c[2] = v.z + 1; c[3] = v.w + 1;
    } else {
        for (int k = 0; k < 4; k++)
            c[k] = (base + k < N) ? counts[base + k] + 1 : 0;
    }
    int sum = c[0] + c[1] + c[2] + c[3];
    int lane = threadIdx.x & 63, wid = threadIdx.x >> 6;
    int s = sum;
    #pragma unroll
    for (int off = 1; off < 64; off <<= 1) {
        int n = __shfl_up(s, off);
        if (lane >= off) s += n;
    }
    __shared__ int wsum[4], wpre[4];
    if (lane == 63) wsum[wid] = s;
    __syncthreads();
    if (threadIdx.x == 0) {
        int a = 0;
        #pragma unroll
        for (int k = 0; k < 4; k++) { wpre[k] = a; a += wsum[k]; }
    }
    __syncthreads();
    int e0 = bsums[blockIdx.x] + wpre[wid] + (s - sum);
    int4 o = make_int4(e0, e0 + c[0], e0 + c[0] + c[1], e0 + c[0] + c[1] + c[2]);
    // deg = counts + 1 = c  -> dinv = rsqrt(deg)
    float4 dv = make_float4(rsqrtf((float)c[0]), rsqrtf((float)c[1]),
                            rsqrtf((float)c[2]), rsqrtf((float)c[3]));
    if (full) {
        *(int4*)(offsets + base) = o;
        *(int4*)(cursor + base) = o;
        *(float4*)(dinv + base) = dv;
    } else {
        int oo[4] = { o.x, o.y, o.z, o.w };
        float dd[4] = { dv.x, dv.y, dv.z, dv.w };
        for (int k = 0; k < 4; k++)
            if (base + k < N) {
                offsets[base + k] = oo[k];
                cursor[base + k] = oo[k];
                dinv[base + k] = dd[k];
            }
    }
}

// ---------- bucket edges by dst (CSR), self-edges appended -----------------
__global__ __launch_bounds__(256) void bucket_kernel(
    const int* __restrict__ src32, const int* __restrict__ dst32,
    const float* __restrict__ dinv, int* __restrict__ cursor,
    int2* __restrict__ edges, int E, int N)
{
    int stride = gridDim.x * blockDim.x;
    int total = E + N;
    for (int e = blockIdx.x * blockDim.x + threadIdx.x; e < total; e += stride) {
        int s, d;
        float nv;
        if (e < E) {
            s = src32[e];
            d = dst32[e];
            nv = dinv[s] * dinv[d];
        } else {
            s = e - E;          // self edge: norm = dinv^2 = 1/deg (exact)
            d = s;
            float dv = dinv[s];
            nv = dv * dv;
        }
        int pos = atomicAdd(&cursor[d], 1);
        edges[pos] = make_int2(s, __float_as_int(nv));
    }
}

// ------- W pre-swizzle to MFMA B-fragment order + fused gate MLP -----------
// Blocks 0..23: swizzle (6144 fragments). Block 24: gate (128 threads).
__global__ __launch_bounds__(256) void wswizzle_gate_kernel(
    const float* __restrict__ W0, const float* __restrict__ W1,
    const float* __restrict__ W2, short8* __restrict__ Wf_hi,
    short8* __restrict__ Wf_lo,
    const float* __restrict__ t, const float* __restrict__ Wg1,
    const float* __restrict__ bg1, const float* __restrict__ Wg2,
    const float* __restrict__ bg2, float* __restrict__ gate)
{
    if (blockIdx.x == 24) {
        __shared__ float u[D];
        int j = threadIdx.x;
        if (j < D) {
            float tv = t[0];
            u[j] = tanhf(tv * Wg1[j] + bg1[j]);
        }
        __syncthreads();
        if (j < D) {
            float s = bg2[j];
            #pragma unroll 8
            for (int k = 0; k < D; k++) s += u[k] * Wg2[k * D + j];
            gate[j] = 1.0f / (1.0f + expf(-s));
        }
        return;
    }
    int f = blockIdx.x * 256 + threadIdx.x;   // 0..6143
    int layer = f >> 11;
    int fi = f & 2047;
    int lane = fi & 63;
    int tt = fi >> 6;                // kc*8 + n
    int kc = tt >> 3, n = tt & 7;
    const float* W = (layer == 0) ? W0 : (layer == 1) ? W1 : W2;
    int krow = kc * 32 + (lane >> 4) * 8;
    int col = n * 16 + (lane & 15);
    short8 hv, lv;
    #pragma unroll
    for (int j = 0; j < 8; j++) {
        float x = W[(size_t)(krow + j) * D + col];
        unsigned hb = bf16_rne(x);
        float hf = __uint_as_float(hb << 16);
        unsigned lb = bf16_rne(x - hf);
        hv[j] = (short)hb;
        lv[j] = (short)lb;
    }
    Wf_hi[f] = hv;
    Wf_lo[f] = lv;
}

// ----------------- split-bf16 MFMA GEMM: H16 = X @ W (fp16 out) ------------
// Block = 128 rows, 4 waves; wave w owns rows [w*32, w*32+32) and stages them
// into its PRIVATE LDS region with global_load_lds (16B/lane), XOR-swizzled.
// Barrier-free pipeline: stage(kc+1) issued before consuming kc; wave-local
// s_waitcnt vmcnt(4). No __syncthreads.
#define GBM 128
__device__ __forceinline__ void cvt8(const float* f, short8& hi, short8& lo) {
    #pragma unroll
    for (int j = 0; j < 8; j++) {
        unsigned hb = bf16_rne(f[j]);
        float hf = __uint_as_float(hb << 16);
        unsigned lb = bf16_rne(f[j] - hf);
        hi[j] = (short)hb;
        lo[j] = (short)lb;
    }
}

__global__ __launch_bounds__(256) void gemm_mfma_kernel(
    const float* __restrict__ X, const short8* __restrict__ Wf_hi,
    const short8* __restrict__ Wf_lo, unsigned short* __restrict__ H16, int M)
{
    __shared__ float Xs[8192];   // 4 waves x 2 bufs x 1024 floats (32KB)
    int tid = threadIdx.x;
    int w = tid >> 6, lane = tid & 63;
    int m16 = lane & 15, qd = lane >> 4;
    int rowbase = blockIdx.x * GBM + w * 32;

    floatx4 acc[2][8];
    #pragma unroll
    for (int rt = 0; rt < 2; rt++)
        #pragma unroll
        for (int n = 0; n < 8; n++)
            acc[rt][n] = (floatx4)(0.f);

    #define STAGE(kc_)                                                      \
        {                                                                   \
            float* buf_ = Xs + w * 2048 + ((kc_) & 1) * 1024;               \
            _Pragma("unroll")                                               \
            for (int i = 0; i < 4; i++) {                                   \
                int s_ = i * 64 + lane;                                     \
                int m_ = s_ >> 3;                                           \
                int g_ = (s_ & 7) ^ (m_ & 7);                               \
                int row_ = rowbase + m_;                                    \
                if (row_ >= M) row_ = M - 1;                                \
                gload_lds16(X + (size_t)row_ * D + (kc_) * 32 + g_ * 4,     \
                            buf_ + i * 256);                                \
            }                                                               \
        }

    STAGE(0)

    #pragma unroll
    for (int kc = 0; kc < 4; kc++) {
        if (kc < 3) STAGE(kc + 1)
        // wave-local wait: leave the 4 newest DMAs (kc+1) outstanding.
        if (kc < 3) __builtin_amdgcn_s_waitcnt(0x0F74);
        else        __builtin_amdgcn_s_waitcnt(0x0F70);

        const float* buf = Xs + w * 2048 + (kc & 1) * 1024;
        float a0[8], a1[8];
        int s00 = m16 * 8 + ((2 * qd) ^ (m16 & 7));
        int s01 = m16 * 8 + ((2 * qd + 1) ^ (m16 & 7));
        int m1 = m16 + 16;
        int s10 = m1 * 8 + ((2 * qd) ^ (m1 & 7));
        int s11 = m1 * 8 + ((2 * qd + 1) ^ (m1 & 7));
        *(float4*)(a0)     = *(const float4*)(buf + s00 * 4);
        *(float4*)(a0 + 4) = *(const float4*)(buf + s01 * 4);
        *(float4*)(a1)     = *(const float4*)(buf + s10 * 4);
        *(float4*)(a1 + 4) = *(const float4*)(buf + s11 * 4);

        short8 ah[2], al[2];
        cvt8(a0, ah[0], al[0]);
        cvt8(a1, ah[1], al[1]);

        #pragma unroll
        for (int n = 0; n < 8; n++) {
            short8 bh = Wf_hi[(size_t)(kc * 8 + n) * 64 + lane];
            short8 bl = Wf_lo[(size_t)(kc * 8 + n) * 64 + lane];
            acc[0][n] = __builtin_amdgcn_mfma_f32_16x16x32_bf16(ah[0], bh, acc[0][n], 0, 0, 0);
            acc[0][n] = __builtin_amdgcn_mfma_f32_16x16x32_bf16(ah[0], bl, acc[0][n], 0, 0, 0);
            acc[0][n] = __builtin_amdgcn_mfma_f32_16x16x32_bf16(al[0], bh, acc[0][n], 0, 0, 0);
            acc[1][n] = __builtin_amdgcn_mfma_f32_16x16x32_bf16(ah[1], bh, acc[1][n], 0, 0, 0);
            acc[1][n] = __builtin_amdgcn_mfma_f32_16x16x32_bf16(ah[1], bl, acc[1][n], 0, 0, 0);
            acc[1][n] = __builtin_amdgcn_mfma_f32_16x16x32_bf16(al[1], bh, acc[1][n], 0, 0, 0);
        }
    }
    #undef STAGE

    // C/D layout: col = n*16 + m16, row = rt*16 + qd*4 + reg; store fp16
    #pragma unroll
    for (int rt = 0; rt < 2; rt++) {
        #pragma unroll
        for (int reg = 0; reg < 4; reg++) {
            int row = rowbase + rt * 16 + qd * 4 + reg;
            if (row < M) {
                unsigned short* hp = H16 + (size_t)row * D + m16;
                #pragma unroll
                for (int n = 0; n < 8; n++)
                    hp[n * 16] = __half_as_ushort(__float2half(acc[rt][n][reg]));
            }
        }
    }
}

// ------- per-node aggregation: half-wave/node, 8-deep PREDICATED chunks ----
// Every node = ceil(deg/8) rounds of 8 independent edge loads + 8 gathers;
// pad slots clamp to end-1 with norm=0 (self-edge guarantees deg>=1).
__global__ __launch_bounds__(256) void agg_kernel(
    const unsigned short* __restrict__ H16, const int2* __restrict__ edges,
    const int* __restrict__ offsets, const float* __restrict__ bias,
    const float* __restrict__ gate, float* __restrict__ out, int M)
{
    int t = threadIdx.x;
    int hw = t >> 5;                  // half-wave 0..7
    int l32 = t & 31;
    int node = blockIdx.x * 8 + hw;
    if (node >= M) return;

    int beg = offsets[node];
    int end = offsets[node + 1];
    const unsigned short* __restrict__ Hc = H16 + l32 * 4;
    float4 acc = make_float4(0.f, 0.f, 0.f, 0.f);

    for (int j = beg; j < end; j += 8) {
        int2 e[8];
        #pragma unroll
        for (int k = 0; k < 8; k++) {
            int idx = j + k;
            e[k] = edges[idx < end ? idx : end - 1];
        }
        ushort4 u[8];
        #pragma unroll
        for (int k = 0; k < 8; k++)
            u[k] = *(const ushort4*)(Hc + (size_t)e[k].x * D);
        #pragma unroll
        for (int k = 0; k < 8; k++) {
            float nv = (j + k < end) ? __int_as_float(e[k].y) : 0.f;
            acc.x = fmaf(h2f(u[k].x), nv, acc.x);
            acc.y = fmaf(h2f(u[k].y), nv, acc.y);
            acc.z = fmaf(h2f(u[k].z), nv, acc.z);
            acc.w = fmaf(h2f(u[k].w), nv, acc.w);
        }
    }

    float4 bv = *(const float4*)(bias + l32 * 4);
    float4 gv = *(const float4*)(gate + l32 * 4);
    acc.x = fmaxf(acc.x + bv.x, 0.f) * gv.x;
    acc.y = fmaxf(acc.y + bv.y, 0.f) * gv.y;
    acc.z = fmaxf(acc.z + bv.z, 0.f) * gv.z;
    acc.w = fmaxf(acc.w + bv.w, 0.f) * gv.w;
    *(float4*)(out + (size_t)node * D + l32 * 4) = acc;
}

// ---------------------------------------------------------------------------
static inline size_t align_up(size_t v, size_t a) { return (v + a - 1) & ~(a - 1); }

extern "C" void kernel_launch(void* const* d_in, const int* in_sizes, int n_in,
                              void* d_out, int out_size, void* d_ws, size_t ws_size,
                              hipStream_t stream)
{
    const float* x   = (const float*)d_in[0];
    const int*   ei  = (const int*)d_in[1];   // int32 or int64 (auto-detected)
    const float* ts  = (const float*)d_in[2];
    const float* Wl[3] = { (const float*)d_in[3], (const float*)d_in[5], (const float*)d_in[7] };
    const float* bl[3] = { (const float*)d_in[4], (const float*)d_in[6], (const float*)d_in[8] };
    const float* Wg1 = (const float*)d_in[9];
    const float* bg1 = (const float*)d_in[10];
    const float* Wg2 = (const float*)d_in[11];
    const float* bg2 = (const float*)d_in[12];

    const int N = in_sizes[0] / D;      // 100000
    const int E = in_sizes[1] / 2;      // 600000
    const int NB = (N + SCHUNK - 1) / SCHUNK;   // scan blocks

    // workspace carve (all 256B aligned)
    char* p = (char*)d_ws;
    unsigned short* h16 = (unsigned short*)p; p += align_up((size_t)N * D * 2, 256);
    float* buf0 = (float*)p; p += align_up((size_t)N * D * 4, 256);
    int* src32  = (int*)p;   p += align_up((size_t)E * 4, 256);
    int* dst32  = (int*)p;   p += align_up((size_t)E * 4, 256);
    int* counts = (int*)p;   p += align_up((size_t)N * 4, 256);
    float* dinv = (float*)p; p += align_up((size_t)N * 4, 256);
    int* offs   = (int*)p;   p += align_up((size_t)(N + 1) * 4, 256);
    int* cursor = (int*)p;   p += align_up((size_t)N * 4, 256);
    int2* edges = (int2*)p;  p += align_up((size_t)(E + N) * 8, 256);
    float* gate = (float*)p; p += align_up((size_t)D * 4, 256);
    int* bsums  = (int*)p;   p += align_up((size_t)NB * 4, 256);
    short8* Wf_hi = (short8*)p; p += align_up((size_t)3 * 2048 * 16, 256);
    short8* Wf_lo = (short8*)p; p += align_up((size_t)3 * 2048 * 16, 256);
    (void)ws_size; (void)n_in; (void)out_size;

    (void)hipMemsetAsync(counts, 0, (size_t)N * 4, stream);
    wswizzle_gate_kernel<<<25, 256, 0, stream>>>(Wl[0], Wl[1], Wl[2], Wf_hi, Wf_lo,
                                                 ts, Wg1, bg1, Wg2, bg2, gate);
    convert_hist_kernel<<<1024, 256, 0, stream>>>(ei, src32, dst32, counts, E);
    scan_partial_kernel<<<NB, 256, 0, stream>>>(counts, bsums, N);
    scan_bsums_kernel<<<1, 1024, 0, stream>>>(bsums, offs + N, NB);
    scan_final_kernel<<<NB, 256, 0, stream>>>(counts, bsums, offs, cursor, dinv, N);
    bucket_kernel<<<1024, 256, 0, stream>>>(src32, dst32, dinv, cursor, edges, E, N);

    const float* xin = x;
    float* outs[3] = { buf0, buf0, (float*)d_out };
    for (int l = 0; l < 3; l++) {
        gemm_mfma_kernel<<<(N + GBM - 1) / GBM, 256, 0, stream>>>(
            xin, Wf_hi + (size_t)l * 2048, Wf_lo + (size_t)l * 2048, h16, N);
        agg_kernel<<<(N + 7) / 8, 256, 0, stream>>>(h16, edges, offs,
                                                    bl[l], gate, outs[l], N);
        xin = outs[l];
    }
}

// Round 9
// 384.119 us; speedup vs baseline: 1.0345x; 1.0345x over previous
//
#include <hip/hip_runtime.h>
#include <hip/hip_bf16.h>
#include <hip/hip_fp16.h>
#include <math.h>

// ---------------------------------------------------------------------------
// DynamicGCN: 3x (GCNConv -> ReLU -> *gate)
// R1: multi-block scan, hist fused into convert, dinv folded into scan C.
// R2: split-bf16 MFMA GEMM, W pre-swizzled into B-fragment order.
// R3/R7: agg 2 nodes/wave (half-wave x float4), 4-deep unroll; H fp16;
//     gemm per-wave global_load_lds barrier-free pipeline (vmcnt(4)).
// R8: 8-deep predicated agg REGRESSED (VGPR 36, occ 53%) -> reverted.
// R9: layer outputs 0/1 stored as PRE-SPLIT bf16 hi/lo planes (same bytes
//     as fp32); layers 1/2 use gemm_bf16_kernel whose K-loop has ZERO
//     conversion VALU (DMA lands directly in A-fragment layout). The f32-in
//     gemm was VALU-bound on the split (~256 VALU vs 24 MFMA per kc).
// ---------------------------------------------------------------------------

#define D 128   // feature dim (D_IN == HID == 128)

typedef __attribute__((ext_vector_type(8))) short short8;
typedef __attribute__((ext_vector_type(4))) float floatx4;

__device__ __forceinline__ unsigned bf16_rne(float x) {
    unsigned u = __float_as_uint(x);
    return (u + 0x7FFFu + ((u >> 16) & 1u)) >> 16;
}

__device__ __forceinline__ void gload_lds16(const void* g, void* l) {
    __builtin_amdgcn_global_load_lds(
        (const __attribute__((address_space(1))) unsigned int*)g,
        (__attribute__((address_space(3))) unsigned int*)l, 16, 0, 0);
}

__device__ __forceinline__ float h2f(unsigned short u) {
    return __half2float(__ushort_as_half(u));
}

// ---- edge_index convert (int64 auto-detect) + fused degree histogram ------
__global__ __launch_bounds__(256) void convert_hist_kernel(
    const int* __restrict__ w, int* __restrict__ src32,
    int* __restrict__ dst32, int* __restrict__ counts, int E)
{
    __shared__ int flag;
    if (threadIdx.x == 0) {
        int z = 0;
        for (int k = 0; k < 64; k++) z |= w[2 * k + 1];
        flag = (z == 0) ? 1 : 0;   // all odd words zero => int64 layout
    }
    __syncthreads();
    int i64 = flag;
    int total = 2 * E;
    int stride = gridDim.x * blockDim.x;
    for (int i = blockIdx.x * blockDim.x + threadIdx.x; i < total; i += stride) {
        int v = i64 ? w[2 * i] : w[i];   // little-endian low word
        if (i < E) {
            src32[i] = v;
        } else {
            dst32[i - E] = v;
            atomicAdd(&counts[v], 1);
        }
    }
}

// ------------------- multi-block exclusive scan ----------------------------
// Scans (counts[i] + 1): CSR capacity includes one self-edge per node.
#define SCHUNK 1024
__global__ __launch_bounds__(256) void scan_partial_kernel(
    const int* __restrict__ counts, int* __restrict__ bsums, int N)
{
    int base = blockIdx.x * SCHUNK + threadIdx.x * 4;
    int s = 0;
    if (base + 3 < N) {
        int4 v = *(const int4*)(counts + base);
        s = v.x + v.y + v.z + v.w + 4;
    } else {
        for (int k = 0; k < 4; k++) if (base + k < N) s += counts[base + k] + 1;
    }
    #pragma unroll
    for (int off = 1; off < 64; off <<= 1) s += __shfl_xor(s, off);
    __shared__ int wsum[4];
    int lane = threadIdx.x & 63, wid = threadIdx.x >> 6;
    if (lane == 0) wsum[wid] = s;
    __syncthreads();
    if (threadIdx.x == 0)
        bsums[blockIdx.x] = wsum[0] + wsum[1] + wsum[2] + wsum[3];
}

__global__ __launch_bounds__(1024) void scan_bsums_kernel(
    int* __restrict__ bsums, int* __restrict__ total_out, int B)
{
    int t = threadIdx.x;
    int v = (t < B) ? bsums[t] : 0;
    int lane = t & 63, wid = t >> 6;
    int s = v;
    #pragma unroll
    for (int off = 1; off < 64; off <<= 1) {
        int n = __shfl_up(s, off);
        if (lane >= off) s += n;
    }
    __shared__ int wsum[16], wpre[16];
    if (lane == 63) wsum[wid] = s;
    __syncthreads();
    if (t < 16) {
        int ws = wsum[t];
        #pragma unroll
        for (int off = 1; off < 16; off <<= 1) {
            int n = __shfl_up(ws, off);
            if (t >= off) ws += n;
        }
        wpre[t] = ws;
    }
    __syncthreads();
    int wex = wid ? wpre[wid - 1] : 0;
    if (t < B) bsums[t] = wex + (s - v);      // exclusive
    if (t == 0) *total_out = wpre[15];        // grand total -> offsets[N]
}

__global__ __launch_bounds__(256) void scan_final_kernel(
    const int* __restrict__ counts, const int* __restrict__ bsums,
    int* __restrict__ offsets, int* __restrict__ cursor,
    float* __restrict__ dinv, int N)
{
    int base = blockIdx.x * SCHUNK + threadIdx.x * 4;
    int c[4];
    bool full = (base + 3 < N);
    if (full) {
        int4 v = *(const int4*)(counts + base);
        c[0] = v.x + 1; c[1] = v.y + 1; c[2] = v.z + 1; c[3] = v.w + 1;
    } else {
        for (int k = 0; k < 4; k++)
            c[k] = (base + k < N) ? counts[base + k] + 1 : 0;
    }
    int sum = c[0] + c[1] + c[2] + c[3];
    int lane = threadIdx.x & 63, wid = threadIdx.x >> 6;
    int s = sum;
    #pragma unroll
    for (int off = 1; off < 64; off <<= 1) {
        int n = __shfl_up(s, off);
        if (lane >= off) s += n;
    }
    __shared__ int wsum[4], wpre[4];
    if (lane == 63) wsum[wid] = s;
    __syncthreads();
    if (threadIdx.x == 0) {
        int a = 0;
        #pragma unroll
        for (int k = 0; k < 4; k++) { wpre[k] = a; a += wsum[k]; }
    }
    __syncthreads();
    int e0 = bsums[blockIdx.x] + wpre[wid] + (s - sum);
    int4 o = make_int4(e0, e0 + c[0], e0 + c[0] + c[1], e0 + c[0] + c[1] + c[2]);
    // deg = counts + 1 = c  -> dinv = rsqrt(deg)
    float4 dv = make_float4(rsqrtf((float)c[0]), rsqrtf((float)c[1]),
                            rsqrtf((float)c[2]), rsqrtf((float)c[3]));
    if (full) {
        *(int4*)(offsets + base) = o;
        *(int4*)(cursor + base) = o;
        *(float4*)(dinv + base) = dv;
    } else {
        int oo[4] = { o.x, o.y, o.z, o.w };
        float dd[4] = { dv.x, dv.y, dv.z, dv.w };
        for (int k = 0; k < 4; k++)
            if (base + k < N) {
                offsets[base + k] = oo[k];
                cursor[base + k] = oo[k];
                dinv[base + k] = dd[k];
            }
    }
}

// ---------- bucket edges by dst (CSR), self-edges appended -----------------
__global__ __launch_bounds__(256) void bucket_kernel(
    const int* __restrict__ src32, const int* __restrict__ dst32,
    const float* __restrict__ dinv, int* __restrict__ cursor,
    int2* __restrict__ edges, int E, int N)
{
    int stride = gridDim.x * blockDim.x;
    int total = E + N;
    for (int e = blockIdx.x * blockDim.x + threadIdx.x; e < total; e += stride) {
        int s, d;
        float nv;
        if (e < E) {
            s = src32[e];
            d = dst32[e];
            nv = dinv[s] * dinv[d];
        } else {
            s = e - E;          // self edge: norm = dinv^2 = 1/deg (exact)
            d = s;
            float dv = dinv[s];
            nv = dv * dv;
        }
        int pos = atomicAdd(&cursor[d], 1);
        edges[pos] = make_int2(s, __float_as_int(nv));
    }
}

// ------- W pre-swizzle to MFMA B-fragment order + fused gate MLP -----------
// Blocks 0..23: swizzle (6144 fragments). Block 24: gate (128 threads).
__global__ __launch_bounds__(256) void wswizzle_gate_kernel(
    const float* __restrict__ W0, const float* __restrict__ W1,
    const float* __restrict__ W2, short8* __restrict__ Wf_hi,
    short8* __restrict__ Wf_lo,
    const float* __restrict__ t, const float* __restrict__ Wg1,
    const float* __restrict__ bg1, const float* __restrict__ Wg2,
    const float* __restrict__ bg2, float* __restrict__ gate)
{
    if (blockIdx.x == 24) {
        __shared__ float u[D];
        int j = threadIdx.x;
        if (j < D) {
            float tv = t[0];
            u[j] = tanhf(tv * Wg1[j] + bg1[j]);
        }
        __syncthreads();
        if (j < D) {
            float s = bg2[j];
            #pragma unroll 8
            for (int k = 0; k < D; k++) s += u[k] * Wg2[k * D + j];
            gate[j] = 1.0f / (1.0f + expf(-s));
        }
        return;
    }
    int f = blockIdx.x * 256 + threadIdx.x;   // 0..6143
    int layer = f >> 11;
    int fi = f & 2047;
    int lane = fi & 63;
    int tt = fi >> 6;                // kc*8 + n
    int kc = tt >> 3, n = tt & 7;
    const float* W = (layer == 0) ? W0 : (layer == 1) ? W1 : W2;
    int krow = kc * 32 + (lane >> 4) * 8;
    int col = n * 16 + (lane & 15);
    short8 hv, lv;
    #pragma unroll
    for (int j = 0; j < 8; j++) {
        float x = W[(size_t)(krow + j) * D + col];
        unsigned hb = bf16_rne(x);
        float hf = __uint_as_float(hb << 16);
        unsigned lb = bf16_rne(x - hf);
        hv[j] = (short)hb;
        lv[j] = (short)lb;
    }
    Wf_hi[f] = hv;
    Wf_lo[f] = lv;
}

// ------------- shared MFMA inner block (A frags in registers) --------------
#define MFMA_BLOCK(kc)                                                        \
    _Pragma("unroll")                                                         \
    for (int n = 0; n < 8; n++) {                                             \
        short8 bh = Wf_hi[(size_t)((kc) * 8 + n) * 64 + lane];                \
        short8 bl = Wf_lo[(size_t)((kc) * 8 + n) * 64 + lane];                \
        acc[0][n] = __builtin_amdgcn_mfma_f32_16x16x32_bf16(ah0, bh, acc[0][n], 0, 0, 0); \
        acc[0][n] = __builtin_amdgcn_mfma_f32_16x16x32_bf16(ah0, bl, acc[0][n], 0, 0, 0); \
        acc[0][n] = __builtin_amdgcn_mfma_f32_16x16x32_bf16(al0, bh, acc[0][n], 0, 0, 0); \
        acc[1][n] = __builtin_amdgcn_mfma_f32_16x16x32_bf16(ah1, bh, acc[1][n], 0, 0, 0); \
        acc[1][n] = __builtin_amdgcn_mfma_f32_16x16x32_bf16(ah1, bl, acc[1][n], 0, 0, 0); \
        acc[1][n] = __builtin_amdgcn_mfma_f32_16x16x32_bf16(al1, bh, acc[1][n], 0, 0, 0); \
    }

#define EPILOGUE()                                                            \
    _Pragma("unroll")                                                         \
    for (int rt = 0; rt < 2; rt++) {                                          \
        _Pragma("unroll")                                                     \
        for (int reg = 0; reg < 4; reg++) {                                   \
            int row = rowbase + rt * 16 + qd * 4 + reg;                       \
            if (row < M) {                                                    \
                unsigned short* hp = H16 + (size_t)row * D + m16;             \
                _Pragma("unroll")                                             \
                for (int n = 0; n < 8; n++)                                   \
                    hp[n * 16] = __half_as_ushort(__float2half(acc[rt][n][reg])); \
            }                                                                 \
        }                                                                     \
    }

// ------------- GEMM variant A: fp32 X input (layer 0 only) -----------------
#define GBM 128
__device__ __forceinline__ void cvt8(const float* f, short8& hi, short8& lo) {
    #pragma unroll
    for (int j = 0; j < 8; j++) {
        unsigned hb = bf16_rne(f[j]);
        float hf = __uint_as_float(hb << 16);
        unsigned lb = bf16_rne(f[j] - hf);
        hi[j] = (short)hb;
        lo[j] = (short)lb;
    }
}

__global__ __launch_bounds__(256) void gemm_f32_kernel(
    const float* __restrict__ X, const short8* __restrict__ Wf_hi,
    const short8* __restrict__ Wf_lo, unsigned short* __restrict__ H16, int M)
{
    __shared__ float Xs[8192];   // 4 waves x 2 bufs x 1024 floats (32KB)
    int tid = threadIdx.x;
    int w = tid >> 6, lane = tid & 63;
    int m16 = lane & 15, qd = lane >> 4;
    int rowbase = blockIdx.x * GBM + w * 32;

    floatx4 acc[2][8];
    #pragma unroll
    for (int rt = 0; rt < 2; rt++)
        #pragma unroll
        for (int n = 0; n < 8; n++)
            acc[rt][n] = (floatx4)(0.f);

    #define STAGE(kc_)                                                      \
        {                                                                   \
            float* buf_ = Xs + w * 2048 + ((kc_) & 1) * 1024;               \
            _Pragma("unroll")                                               \
            for (int i = 0; i < 4; i++) {                                   \
                int s_ = i * 64 + lane;                                     \
                int m_ = s_ >> 3;                                           \
                int g_ = (s_ & 7) ^ (m_ & 7);                               \
                int row_ = rowbase + m_;                                    \
                if (row_ >= M) row_ = M - 1;                                \
                gload_lds16(X + (size_t)row_ * D + (kc_) * 32 + g_ * 4,     \
                            buf_ + i * 256);                                \
            }                                                               \
        }

    STAGE(0)

    #pragma unroll
    for (int kc = 0; kc < 4; kc++) {
        if (kc < 3) STAGE(kc + 1)
        if (kc < 3) __builtin_amdgcn_s_waitcnt(0x0F74);
        else        __builtin_amdgcn_s_waitcnt(0x0F70);

        const float* buf = Xs + w * 2048 + (kc & 1) * 1024;
        float a0[8], a1[8];
        int s00 = m16 * 8 + ((2 * qd) ^ (m16 & 7));
        int s01 = m16 * 8 + ((2 * qd + 1) ^ (m16 & 7));
        int m1 = m16 + 16;
        int s10 = m1 * 8 + ((2 * qd) ^ (m1 & 7));
        int s11 = m1 * 8 + ((2 * qd + 1) ^ (m1 & 7));
        *(float4*)(a0)     = *(const float4*)(buf + s00 * 4);
        *(float4*)(a0 + 4) = *(const float4*)(buf + s01 * 4);
        *(float4*)(a1)     = *(const float4*)(buf + s10 * 4);
        *(float4*)(a1 + 4) = *(const float4*)(buf + s11 * 4);

        short8 ah0, al0, ah1, al1;
        cvt8(a0, ah0, al0);
        cvt8(a1, ah1, al1);
        MFMA_BLOCK(kc)
    }
    #undef STAGE
    EPILOGUE()
}

// ------ GEMM variant B: pre-split bf16 hi/lo planes input (layers 1,2) -----
// DMA lands directly in A-fragment layout: flat chunk f = i*64+lane maps to
// row m=f>>2, frag g=f&3; LDS slot (m*4+g) holds A[m][kc*32+g*8..+7].
// K-loop has ZERO conversion VALU.
__global__ __launch_bounds__(256) void gemm_bf16_kernel(
    const unsigned short* __restrict__ Xh, const unsigned short* __restrict__ Xl,
    const short8* __restrict__ Wf_hi, const short8* __restrict__ Wf_lo,
    unsigned short* __restrict__ H16, int M)
{
    __shared__ short lds[16384]; // 4 waves x 2 bufs x (hi 1024 + lo 1024) shorts
    int tid = threadIdx.x;
    int w = tid >> 6, lane = tid & 63;
    int m16 = lane & 15, qd = lane >> 4;
    int rowbase = blockIdx.x * GBM + w * 32;

    floatx4 acc[2][8];
    #pragma unroll
    for (int rt = 0; rt < 2; rt++)
        #pragma unroll
        for (int n = 0; n < 8; n++)
            acc[rt][n] = (floatx4)(0.f);

    #define STAGEB(kc_)                                                     \
        {                                                                   \
            short* bh_ = lds + w * 4096 + ((kc_) & 1) * 2048;               \
            short* bl_ = bh_ + 1024;                                        \
            _Pragma("unroll")                                               \
            for (int i = 0; i < 2; i++) {                                   \
                int f_ = i * 64 + lane;                                     \
                int m_ = f_ >> 2;                                           \
                int g_ = f_ & 3;                                            \
                int row_ = rowbase + m_;                                    \
                if (row_ >= M) row_ = M - 1;                                \
                size_t go_ = (size_t)row_ * D + (kc_) * 32 + g_ * 8;        \
                gload_lds16(Xh + go_, bh_ + i * 512);                       \
                gload_lds16(Xl + go_, bl_ + i * 512);                       \
            }                                                               \
        }

    STAGEB(0)

    #pragma unroll
    for (int kc = 0; kc < 4; kc++) {
        if (kc < 3) STAGEB(kc + 1)
        if (kc < 3) __builtin_amdgcn_s_waitcnt(0x0F74);
        else        __builtin_amdgcn_s_waitcnt(0x0F70);

        const short* bh_cur = lds + w * 4096 + (kc & 1) * 2048;
        const short* bl_cur = bh_cur + 1024;
        short8 ah0 = *(const short8*)(bh_cur + (m16 * 4 + qd) * 8);
        short8 ah1 = *(const short8*)(bh_cur + ((m16 + 16) * 4 + qd) * 8);
        short8 al0 = *(const short8*)(bl_cur + (m16 * 4 + qd) * 8);
        short8 al1 = *(const short8*)(bl_cur + ((m16 + 16) * 4 + qd) * 8);
        MFMA_BLOCK(kc)
    }
    #undef STAGEB
    EPILOGUE()
}

// ------- per-node aggregation (R7 loop): half-wave/node, 4-deep + tail -----
// mode: writeF32 != 0 -> fp32 to outF (final layer); else pre-split bf16
// hi/lo planes to outH/outL (input for next layer's gemm_bf16_kernel).
__global__ __launch_bounds__(256) void agg_kernel(
    const unsigned short* __restrict__ H16, const int2* __restrict__ edges,
    const int* __restrict__ offsets, const float* __restrict__ bias,
    const float* __restrict__ gate, float* __restrict__ outF,
    unsigned short* __restrict__ outH, unsigned short* __restrict__ outL,
    int M, int writeF32)
{
    int t = threadIdx.x;
    int hw = t >> 5;                  // half-wave 0..7
    int l32 = t & 31;
    int node = blockIdx.x * 8 + hw;
    if (node >= M) return;

    int beg = offsets[node];
    int end = offsets[node + 1];
    const unsigned short* __restrict__ Hc = H16 + l32 * 4;
    float4 acc = make_float4(0.f, 0.f, 0.f, 0.f);

    int j = beg;
    for (; j + 4 <= end; j += 4) {
        int2 e0 = edges[j + 0];
        int2 e1 = edges[j + 1];
        int2 e2 = edges[j + 2];
        int2 e3 = edges[j + 3];
        ushort4 u0 = *(const ushort4*)(Hc + (size_t)e0.x * D);
        ushort4 u1 = *(const ushort4*)(Hc + (size_t)e1.x * D);
        ushort4 u2 = *(const ushort4*)(Hc + (size_t)e2.x * D);
        ushort4 u3 = *(const ushort4*)(Hc + (size_t)e3.x * D);
        float n0 = __int_as_float(e0.y), n1 = __int_as_float(e1.y);
        float n2 = __int_as_float(e2.y), n3 = __int_as_float(e3.y);
        acc.x = fmaf(h2f(u3.x), n3, fmaf(h2f(u2.x), n2, fmaf(h2f(u1.x), n1, fmaf(h2f(u0.x), n0, acc.x))));
        acc.y = fmaf(h2f(u3.y), n3, fmaf(h2f(u2.y), n2, fmaf(h2f(u1.y), n1, fmaf(h2f(u0.y), n0, acc.y))));
        acc.z = fmaf(h2f(u3.z), n3, fmaf(h2f(u2.z), n2, fmaf(h2f(u1.z), n1, fmaf(h2f(u0.z), n0, acc.z))));
        acc.w = fmaf(h2f(u3.w), n3, fmaf(h2f(u2.w), n2, fmaf(h2f(u1.w), n1, fmaf(h2f(u0.w), n0, acc.w))));
    }
    for (; j < end; j++) {
        int2 e = edges[j];
        float nv = __int_as_float(e.y);
        ushort4 u = *(const ushort4*)(Hc + (size_t)e.x * D);
        acc.x = fmaf(h2f(u.x), nv, acc.x);
        acc.y = fmaf(h2f(u.y), nv, acc.y);
        acc.z = fmaf(h2f(u.z), nv, acc.z);
        acc.w = fmaf(h2f(u.w), nv, acc.w);
    }

    float4 bv = *(const float4*)(bias + l32 * 4);
    float4 gv = *(const float4*)(gate + l32 * 4);
    acc.x = fmaxf(acc.x + bv.x, 0.f) * gv.x;
    acc.y = fmaxf(acc.y + bv.y, 0.f) * gv.y;
    acc.z = fmaxf(acc.z + bv.z, 0.f) * gv.z;
    acc.w = fmaxf(acc.w + bv.w, 0.f) * gv.w;

    if (writeF32) {
        *(float4*)(outF + (size_t)node * D + l32 * 4) = acc;
    } else {
        unsigned hx = bf16_rne(acc.x), hy = bf16_rne(acc.y);
        unsigned hz = bf16_rne(acc.z), hw4 = bf16_rne(acc.w);
        ushort4 hs = make_ushort4((unsigned short)hx, (unsigned short)hy,
                                  (unsigned short)hz, (unsigned short)hw4);
        ushort4 ls = make_ushort4(
            (unsigned short)bf16_rne(acc.x - __uint_as_float(hx << 16)),
            (unsigned short)bf16_rne(acc.y - __uint_as_float(hy << 16)),
            (unsigned short)bf16_rne(acc.z - __uint_as_float(hz << 16)),
            (unsigned short)bf16_rne(acc.w - __uint_as_float(hw4 << 16)));
        *(ushort4*)(outH + (size_t)node * D + l32 * 4) = hs;
        *(ushort4*)(outL + (size_t)node * D + l32 * 4) = ls;
    }
}

// ---------------------------------------------------------------------------
static inline size_t align_up(size_t v, size_t a) { return (v + a - 1) & ~(a - 1); }

extern "C" void kernel_launch(void* const* d_in, const int* in_sizes, int n_in,
                              void* d_out, int out_size, void* d_ws, size_t ws_size,
                              hipStream_t stream)
{
    const float* x   = (const float*)d_in[0];
    const int*   ei  = (const int*)d_in[1];   // int32 or int64 (auto-detected)
    const float* ts  = (const float*)d_in[2];
    const float* Wl[3] = { (const float*)d_in[3], (const float*)d_in[5], (const float*)d_in[7] };
    const float* bl[3] = { (const float*)d_in[4], (const float*)d_in[6], (const float*)d_in[8] };
    const float* Wg1 = (const float*)d_in[9];
    const float* bg1 = (const float*)d_in[10];
    const float* Wg2 = (const float*)d_in[11];
    const float* bg2 = (const float*)d_in[12];

    const int N = in_sizes[0] / D;      // 100000
    const int E = in_sizes[1] / 2;      // 600000
    const int NB = (N + SCHUNK - 1) / SCHUNK;   // scan blocks

    // workspace carve (all 256B aligned)
    char* p = (char*)d_ws;
    unsigned short* h16 = (unsigned short*)p; p += align_up((size_t)N * D * 2, 256);
    unsigned short* xh  = (unsigned short*)p; p += align_up((size_t)N * D * 2, 256);
    unsigned short* xl  = (unsigned short*)p; p += align_up((size_t)N * D * 2, 256);
    int* src32  = (int*)p;   p += align_up((size_t)E * 4, 256);
    int* dst32  = (int*)p;   p += align_up((size_t)E * 4, 256);
    int* counts = (int*)p;   p += align_up((size_t)N * 4, 256);
    float* dinv = (float*)p; p += align_up((size_t)N * 4, 256);
    int* offs   = (int*)p;   p += align_up((size_t)(N + 1) * 4, 256);
    int* cursor = (int*)p;   p += align_up((size_t)N * 4, 256);
    int2* edges = (int2*)p;  p += align_up((size_t)(E + N) * 8, 256);
    float* gate = (float*)p; p += align_up((size_t)D * 4, 256);
    int* bsums  = (int*)p;   p += align_up((size_t)NB * 4, 256);
    short8* Wf_hi = (short8*)p; p += align_up((size_t)3 * 2048 * 16, 256);
    short8* Wf_lo = (short8*)p; p += align_up((size_t)3 * 2048 * 16, 256);
    (void)ws_size; (void)n_in; (void)out_size;

    (void)hipMemsetAsync(counts, 0, (size_t)N * 4, stream);
    wswizzle_gate_kernel<<<25, 256, 0, stream>>>(Wl[0], Wl[1], Wl[2], Wf_hi, Wf_lo,
                                                 ts, Wg1, bg1, Wg2, bg2, gate);
    convert_hist_kernel<<<1024, 256, 0, stream>>>(ei, src32, dst32, counts, E);
    scan_partial_kernel<<<NB, 256, 0, stream>>>(counts, bsums, N);
    scan_bsums_kernel<<<1, 1024, 0, stream>>>(bsums, offs + N, NB);
    scan_final_kernel<<<NB, 256, 0, stream>>>(counts, bsums, offs, cursor, dinv, N);
    bucket_kernel<<<1024, 256, 0, stream>>>(src32, dst32, dinv, cursor, edges, E, N);

    int ggrid = (N + GBM - 1) / GBM;
    int agrid = (N + 7) / 8;
    // layer 0: fp32 input
    gemm_f32_kernel<<<ggrid, 256, 0, stream>>>(x, Wf_hi, Wf_lo, h16, N);
    agg_kernel<<<agrid, 256, 0, stream>>>(h16, edges, offs, bl[0], gate,
                                          nullptr, xh, xl, N, 0);
    // layer 1: bf16-plane input
    gemm_bf16_kernel<<<ggrid, 256, 0, stream>>>(xh, xl, Wf_hi + 2048, Wf_lo + 2048, h16, N);
    agg_kernel<<<agrid, 256, 0, stream>>>(h16, edges, offs, bl[1], gate,
                                          nullptr, xh, xl, N, 0);
    // layer 2: bf16-plane input, fp32 output
    gemm_bf16_kernel<<<ggrid, 256, 0, stream>>>(xh, xl, Wf_hi + 4096, Wf_lo + 4096, h16, N);
    agg_kernel<<<agrid, 256, 0, stream>>>(h16, edges, offs, bl[2], gate,
                                          (float*)d_out, nullptr, nullptr, N, 1);
}